// Round 3
// baseline (135.729 us; speedup 1.0000x reference)
//
#include <hip/hip_runtime.h>
#include <hip/hip_bf16.h>

#define SEQ 2048
#define DM  1024
#define NH  16
#define HD  64
#define BH  32
#define QB  128
#define KVB 64
#define NT  (SEQ/KVB)
#define TILE_E (KVB*HD)     // 4096 bf16 per tile

#define KWS_OFF 0u
#define VWS_OFF 4194304u    // 32*2048*64

typedef __bf16 bf16x8 __attribute__((ext_vector_type(8)));
typedef __bf16 bf16x4 __attribute__((ext_vector_type(4)));
typedef float  f32x4  __attribute__((ext_vector_type(4)));

// swizzle within a [32 q][64 k] bf16 tile: elem col ^= (row&7)<<3
__device__ __forceinline__ int swp(int row, int c) {
    return row * 64 + (c ^ ((row & 7) << 3));
}

// ---- prep: K -> bf16 [bh][s][d]; V -> bf16 transposed [bh][t][d][kv] ----
__global__ __launch_bounds__(256) void psa_prep(
    const float* __restrict__ V, const float* __restrict__ K,
    __bf16* __restrict__ ws)
{
    const int blk = blockIdx.x;
    if (blk < 2048) {
        const int idx = blk * 256 + threadIdx.x;          // (bh, s, c8)
        const int c8 = idx & 7, s = (idx >> 3) & 2047, bh = idx >> 14;
        const int b = bh >> 4, h = bh & 15;
        const float* src = K + ((size_t)(b * SEQ + s)) * DM + h * HD + c8 * 8;
        float4 a = *(const float4*)src, c = *(const float4*)(src + 4);
        bf16x8 o;
        o[0] = (__bf16)a.x; o[1] = (__bf16)a.y; o[2] = (__bf16)a.z; o[3] = (__bf16)a.w;
        o[4] = (__bf16)c.x; o[5] = (__bf16)c.y; o[6] = (__bf16)c.z; o[7] = (__bf16)c.w;
        *(bf16x8*)(ws + KWS_OFF + (size_t)idx * 8) = o;
    } else {
        const int idx = (blk - 2048) * 256 + threadIdx.x; // (bh, t, kv, c8)
        const int c8 = idx & 7, kv = (idx >> 3) & 63, t = (idx >> 9) & 31, bh = idx >> 14;
        const int b = bh >> 4, h = bh & 15;
        const float* src = V + ((size_t)(b * SEQ + t * 64 + kv)) * DM + h * HD + c8 * 8;
        float4 a = *(const float4*)src, c = *(const float4*)(src + 4);
        __bf16* dst = ws + VWS_OFF + (((size_t)(bh * 32 + t) * 64 + c8 * 8) * 64 + kv);
        dst[0 * 64] = (__bf16)a.x; dst[1 * 64] = (__bf16)a.y;
        dst[2 * 64] = (__bf16)a.z; dst[3 * 64] = (__bf16)a.w;
        dst[4 * 64] = (__bf16)c.x; dst[5 * 64] = (__bf16)c.y;
        dst[6 * 64] = (__bf16)c.z; dst[7 * 64] = (__bf16)c.w;
    }
}

// ---- main: barrier-free, K/V frags direct from L1/L2, double-buffered regs ----
__global__ __launch_bounds__(256, 2) void psa_main(
    const __bf16* __restrict__ ws, const float* __restrict__ Qg,
    float* __restrict__ Og)
{
    __shared__ __bf16 PT[4][QB / 4 * KVB];   // per-wave [32 q][64 k] swizzled

    const int bid = blockIdx.x;
    const int swz = (bid & 7) * 64 + (bid >> 3);   // XCD-aware; 512 % 8 == 0
    const int bh  = swz >> 4;
    const int qb  = swz & 15;
    const int b   = bh >> 4, h = bh & 15;
    const int tid = threadIdx.x;
    const int w   = tid >> 6;
    const int l   = tid & 63;
    const int c16 = l & 15;
    const int seg = l >> 4;
    const int q0  = qb * QB + w * 32;

    const __bf16* Kb = ws + KWS_OFF + (size_t)bh * SEQ * HD;
    const __bf16* Vb = ws + VWS_OFF + (size_t)bh * SEQ * HD;
    const int loff = c16 * 64 + seg * 8;           // lane offset within a 64x64 tile

    // Q fragments from fp32 (read once) — B-layout: col q = q0+qi*16+c16, k = d
    bf16x8 qf[2][2];
#pragma unroll
    for (int qi = 0; qi < 2; ++qi)
#pragma unroll
        for (int ds = 0; ds < 2; ++ds) {
            const float* p = Qg + ((size_t)b * SEQ + q0 + qi * 16 + c16) * DM + h * HD + ds * 32 + seg * 8;
            float4 a = *(const float4*)p, c = *(const float4*)(p + 4);
            bf16x8 o;
            o[0] = (__bf16)a.x; o[1] = (__bf16)a.y; o[2] = (__bf16)a.z; o[3] = (__bf16)a.w;
            o[4] = (__bf16)c.x; o[5] = (__bf16)c.y; o[6] = (__bf16)c.z; o[7] = (__bf16)c.w;
            qf[qi][ds] = o;
        }

    f32x4 acc[2][4];
#pragma unroll
    for (int qi = 0; qi < 2; ++qi)
#pragma unroll
        for (int dt = 0; dt < 4; ++dt)
#pragma unroll
            for (int r = 0; r < 4; ++r) acc[qi][dt][r] = 0.f;

    auto loadf = [&](bf16x8* kf, bf16x8* vf, int t) {
        const __bf16* kp = Kb + (size_t)t * TILE_E + loff;
        const __bf16* vp = Vb + (size_t)t * TILE_E + loff;
#pragma unroll
        for (int i = 0; i < 4; ++i) {
            kf[i * 2]     = *(const bf16x8*)(kp + i * 1024);        // d-slice 0
            kf[i * 2 + 1] = *(const bf16x8*)(kp + i * 1024 + 32);   // d-slice 1
            vf[i * 2]     = *(const bf16x8*)(vp + i * 1024);        // kc 0
            vf[i * 2 + 1] = *(const bf16x8*)(vp + i * 1024 + 32);   // kc 1
        }
    };

    auto compute = [&](const bf16x8* kf, const bf16x8* vf) {
        // QK^T (A=K, B=Q) -> silu -> PT
#pragma unroll
        for (int kt = 0; kt < 4; ++kt)
#pragma unroll
            for (int qi = 0; qi < 2; ++qi) {
                f32x4 s;
#pragma unroll
                for (int r = 0; r < 4; ++r) s[r] = 0.f;
                s = __builtin_amdgcn_mfma_f32_16x16x32_bf16(kf[kt * 2],     qf[qi][0], s, 0, 0, 0);
                s = __builtin_amdgcn_mfma_f32_16x16x32_bf16(kf[kt * 2 + 1], qf[qi][1], s, 0, 0, 0);
                bf16x4 pw;
#pragma unroll
                for (int r = 0; r < 4; ++r) {
                    float x = s[r];
                    float e = __expf(-x);
                    pw[r] = (__bf16)(x * __builtin_amdgcn_rcpf(1.f + e));
                }
                *(bf16x4*)&PT[w][swp(qi * 16 + c16, kt * 16 + seg * 4)] = pw;
            }
        // PV (A=P from LDS, B=V^T regs)
#pragma unroll
        for (int kc = 0; kc < 2; ++kc)
#pragma unroll
            for (int qi = 0; qi < 2; ++qi) {
                bf16x8 pa = *(const bf16x8*)&PT[w][swp(qi * 16 + c16, kc * 32 + seg * 8)];
#pragma unroll
                for (int dt = 0; dt < 4; ++dt)
                    acc[qi][dt] = __builtin_amdgcn_mfma_f32_16x16x32_bf16(pa, vf[dt * 2 + kc], acc[qi][dt], 0, 0, 0);
            }
    };

    bf16x8 ka[8], va[8], kb[8], vb[8];
    loadf(ka, va, 0);
    loadf(kb, vb, 1);

    for (int t = 0; t < NT; t += 2) {
        compute(ka, va);
        if (t + 2 < NT) loadf(ka, va, t + 2);
        compute(kb, vb);
        if (t + 3 < NT) loadf(kb, vb, t + 3);
    }

    // epilogue: D layout col=c16(+dt*16) -> d, row=seg*4+r(+qi*16) -> q
    float* op = Og + ((size_t)b * SEQ + q0) * DM + h * HD;
#pragma unroll
    for (int qi = 0; qi < 2; ++qi)
#pragma unroll
        for (int dt = 0; dt < 4; ++dt)
#pragma unroll
            for (int r = 0; r < 4; ++r)
                op[(size_t)(qi * 16 + seg * 4 + r) * DM + dt * 16 + c16] = acc[qi][dt][r];
}

extern "C" void kernel_launch(void* const* d_in, const int* in_sizes, int n_in,
                              void* d_out, int out_size, void* d_ws, size_t ws_size,
                              hipStream_t stream) {
    const float* v = (const float*)d_in[0];
    const float* k = (const float*)d_in[1];
    const float* q = (const float*)d_in[2];
    float* out = (float*)d_out;
    __bf16* ws = (__bf16*)d_ws;
    (void)in_sizes; (void)n_in; (void)out_size; (void)ws_size;

    psa_prep<<<dim3(4096), dim3(256), 0, stream>>>(v, k, ws);
    psa_main<<<dim3(BH * (SEQ / QB)), dim3(256), 0, stream>>>(ws, q, out);
}

// Round 4
// 83.575 us; speedup vs baseline: 1.6241x; 1.6241x over previous
//
#include <hip/hip_runtime.h>
#include <hip/hip_bf16.h>

#define SEQ 2048
#define DM  1024
#define NH  16
#define HD  64
#define BH  32
#define QB  64            // q rows per block (4 waves x 16)
#define KVB 64
#define NT  (SEQ/KVB)     // 32 tiles
#define TILE_E (KVB*HD)   // 4096 bf16 per tile

#define KWS_OFF 0u        // [BH][NT][64 key][64 d]  swizzle baked
#define VWS_OFF 4194304u  // [BH][NT][64 d][64 kv]   transposed, swizzle baked

typedef __bf16 bf16x8 __attribute__((ext_vector_type(8)));
typedef __bf16 bf16x4 __attribute__((ext_vector_type(4)));
typedef float  f32x4  __attribute__((ext_vector_type(4)));

// swizzled element offset in a [R][64] bf16 tile (row stride 128B)
__device__ __forceinline__ int sw64(int row, int c) {
    return row * 64 + (c ^ ((row & 7) << 3));
}

// ---- prep: K/V fp32 -> bf16 head-split tiles, V transposed, swizzle pre-baked ----
__global__ __launch_bounds__(256) void psa_prep(
    const float* __restrict__ V, const float* __restrict__ K,
    __bf16* __restrict__ ws)
{
    const int blk = blockIdx.x;
    if (blk < 2048) {
        // K chunk (bh, t, key, cb): contents K[b][t*64+key][h*64+d0..+7], d0=((cb^(key&7))<<3)
        const int idx = blk * 256 + threadIdx.x;
        const int cb = idx & 7, key = (idx >> 3) & 63, t = (idx >> 9) & 31, bh = idx >> 14;
        const int b = bh >> 4, h = bh & 15;
        const int d0 = ((cb ^ (key & 7)) << 3);
        const float* src = K + ((size_t)(b * SEQ + t * 64 + key)) * DM + h * HD + d0;
        float4 a = *(const float4*)src, c = *(const float4*)(src + 4);
        bf16x8 o;
        o[0] = (__bf16)a.x; o[1] = (__bf16)a.y; o[2] = (__bf16)a.z; o[3] = (__bf16)a.w;
        o[4] = (__bf16)c.x; o[5] = (__bf16)c.y; o[6] = (__bf16)c.z; o[7] = (__bf16)c.w;
        *(bf16x8*)(ws + KWS_OFF + (size_t)idx * 8) = o;
    } else {
        // V chunk (bh, t, d, cb): contents V[b][t*64+ks0+j][h*64+d], ks0=((cb^(d&7))<<3)
        const int idx = (blk - 2048) * 256 + threadIdx.x;
        const int cb = idx & 7, d = (idx >> 3) & 63, t = (idx >> 9) & 31, bh = idx >> 14;
        const int b = bh >> 4, h = bh & 15;
        const int ks0 = ((cb ^ (d & 7)) << 3);
        const float* src = V + ((size_t)(b * SEQ + t * 64 + ks0)) * DM + h * HD + d;
        bf16x8 o;
#pragma unroll
        for (int j = 0; j < 8; ++j) o[j] = (__bf16)src[(size_t)j * DM];
        *(bf16x8*)(ws + VWS_OFF + (size_t)idx * 8) = o;
    }
}

// ---- main: 4 waves x 16 q-rows, DMA-staged K/V, 4 blocks/CU ----
__global__ __launch_bounds__(256, 4) void psa_main(
    const __bf16* __restrict__ ws, const float* __restrict__ Qg,
    float* __restrict__ Og)
{
    __shared__ __bf16 KT[2][TILE_E];      // 8 KB x2
    __shared__ __bf16 VT[2][TILE_E];      // 8 KB x2
    __shared__ __bf16 PT[4][16 * KVB];    // per-wave [16 q][64 k] swizzled, 2 KB ea

    const int bid = blockIdx.x;
    const int swz = (bid & 7) * 128 + (bid >> 3);   // XCD-aware; 1024 % 8 == 0
    const int bh  = swz >> 5;
    const int qb  = swz & 31;
    const int b   = bh >> 4, h = bh & 15;
    const int tid = threadIdx.x;
    const int w   = tid >> 6;
    const int l   = tid & 63;
    const int c16 = l & 15;
    const int seg = l >> 4;
    const int q0  = qb * QB + w * 16;

    const __bf16* Kws = ws + KWS_OFF;
    const __bf16* Vws = ws + VWS_OFF;

    // Q fragment (B-layout: lane holds col q = q0+c16, k-dim d = ds*32+seg*8+j)
    bf16x8 qf[2];
#pragma unroll
    for (int ds = 0; ds < 2; ++ds) {
        const float* p = Qg + ((size_t)b * SEQ + q0 + c16) * DM + h * HD + ds * 32 + seg * 8;
        float4 a = *(const float4*)p, c = *(const float4*)(p + 4);
        bf16x8 o;
        o[0] = (__bf16)a.x; o[1] = (__bf16)a.y; o[2] = (__bf16)a.z; o[3] = (__bf16)a.w;
        o[4] = (__bf16)c.x; o[5] = (__bf16)c.y; o[6] = (__bf16)c.z; o[7] = (__bf16)c.w;
        qf[ds] = o;
    }

    f32x4 acc[4];
#pragma unroll
    for (int dt = 0; dt < 4; ++dt)
#pragma unroll
        for (int r = 0; r < 4; ++r) acc[dt][r] = 0.f;

    auto stage = [&](int bf, int t) {
        const size_t tb = ((size_t)bh * NT + t) * TILE_E;
#pragma unroll
        for (int i = 0; i < 2; ++i) {
            const int ch  = w * 2 + i;              // 8 x 1KB chunks per tensor
            const int off = ch * 512 + l * 8;
            __builtin_amdgcn_global_load_lds(
                (const __attribute__((address_space(1))) void*)(Kws + tb + off),
                (__attribute__((address_space(3))) void*)&KT[bf][ch * 512], 16, 0, 0);
            __builtin_amdgcn_global_load_lds(
                (const __attribute__((address_space(1))) void*)(Vws + tb + off),
                (__attribute__((address_space(3))) void*)&VT[bf][ch * 512], 16, 0, 0);
        }
    };

    stage(0, 0);
    __syncthreads();

    for (int t = 0; t < NT; ++t) {
        const int cur = t & 1;
        if (t + 1 < NT) stage(cur ^ 1, t + 1);   // prefetch next (drained at tile-end barrier)

        // ---- QK^T (swapped A=K, B=Q) -> silu -> PT (b64 writes, 4 keys/lane)
#pragma unroll
        for (int kt = 0; kt < 4; ++kt) {
            bf16x8 kf0 = *(const bf16x8*)&KT[cur][sw64(kt * 16 + c16, seg * 8)];
            bf16x8 kf1 = *(const bf16x8*)&KT[cur][sw64(kt * 16 + c16, 32 + seg * 8)];
            f32x4 s;
#pragma unroll
            for (int r = 0; r < 4; ++r) s[r] = 0.f;
            __builtin_amdgcn_s_setprio(1);
            s = __builtin_amdgcn_mfma_f32_16x16x32_bf16(kf0, qf[0], s, 0, 0, 0);
            s = __builtin_amdgcn_mfma_f32_16x16x32_bf16(kf1, qf[1], s, 0, 0, 0);
            __builtin_amdgcn_s_setprio(0);
            bf16x4 pw;
#pragma unroll
            for (int r = 0; r < 4; ++r) {
                float x = s[r];
                float e = __expf(-x);
                pw[r] = (__bf16)(x * __builtin_amdgcn_rcpf(1.f + e));
            }
            // D layout: q-col = c16, key = kt*16 + seg*4 + r
            *(bf16x4*)&PT[w][sw64(c16, kt * 16 + seg * 4)] = pw;
        }

        // ---- out += P * V  (A = P row q=c16, B = V^T col d=dt*16+c16)
#pragma unroll
        for (int kc = 0; kc < 2; ++kc) {
            bf16x8 pa = *(const bf16x8*)&PT[w][sw64(c16, kc * 32 + seg * 8)];
            __builtin_amdgcn_s_setprio(1);
#pragma unroll
            for (int dt = 0; dt < 4; ++dt) {
                bf16x8 vf = *(const bf16x8*)&VT[cur][sw64(dt * 16 + c16, kc * 32 + seg * 8)];
                acc[dt] = __builtin_amdgcn_mfma_f32_16x16x32_bf16(pa, vf, acc[dt], 0, 0, 0);
            }
            __builtin_amdgcn_s_setprio(0);
        }

        __syncthreads();
    }

    // ---- epilogue: D layout row q = seg*4+r, col d = dt*16+c16
    float* op = Og + ((size_t)b * SEQ + q0) * DM + h * HD;
#pragma unroll
    for (int dt = 0; dt < 4; ++dt)
#pragma unroll
        for (int r = 0; r < 4; ++r)
            op[(size_t)(seg * 4 + r) * DM + dt * 16 + c16] = acc[dt][r];
}

extern "C" void kernel_launch(void* const* d_in, const int* in_sizes, int n_in,
                              void* d_out, int out_size, void* d_ws, size_t ws_size,
                              hipStream_t stream) {
    const float* v = (const float*)d_in[0];
    const float* k = (const float*)d_in[1];
    const float* q = (const float*)d_in[2];
    float* out = (float*)d_out;
    __bf16* ws = (__bf16*)d_ws;
    (void)in_sizes; (void)n_in; (void)out_size; (void)ws_size;

    psa_prep<<<dim3(4096), dim3(256), 0, stream>>>(v, k, ws);
    psa_main<<<dim3(BH * (SEQ / QB)), dim3(256), 0, stream>>>(ws, q, out);
}